// Round 8
// baseline (684.927 us; speedup 1.0000x reference)
//
#include <hip/hip_runtime.h>

#define DEV __device__ __forceinline__
DEV float relu_(float x) { return fmaxf(x, 0.0f); }

typedef __attribute__((ext_vector_type(4))) float f32x4;
typedef __attribute__((ext_vector_type(8))) __bf16 bf16x8;

DEV void knn_insert(float (&bd)[5], int (&bi)[5], float d, int j) {
  if (d >= bd[4]) return;
  bd[4] = d; bi[4] = j;
#pragma unroll
  for (int p = 4; p > 0; --p) {
    if (bd[p] < bd[p - 1]) {
      float td = bd[p]; bd[p] = bd[p - 1]; bd[p - 1] = td;
      int ti = bi[p]; bi[p] = bi[p - 1]; bi[p - 1] = ti;
    }
  }
}

// branchless EXACT top-5 insert: strict-< bubble, identical semantics to knn_insert
// (new item placed after equal-distance existing items; keeps 5 smallest, sorted)
DEV void knn_insert_bl(float (&bd)[5], int (&bi)[5], float d, int j) {
#pragma unroll
  for (int p = 0; p < 5; ++p) {
    bool lt = d < bd[p];
    float nd = lt ? d : bd[p];
    float cd = lt ? bd[p] : d;
    int ni = lt ? j : bi[p];
    int ci = lt ? bi[p] : j;
    bd[p] = nd; d = cd;
    bi[p] = ni; j = ci;
  }
}

// ---------------- Kernel 1: kNN on pos (F=3), 4-way candidate split ----------------
__global__ __launch_bounds__(256) void k_knn1(const float* __restrict__ pos,
                                              int* __restrict__ idx1) {
  __shared__ float ps[6144];
  __shared__ float sqs[2048];
  __shared__ float md[640];
  __shared__ int mi[640];
  int tid = threadIdx.x;
  int b = blockIdx.x >> 5, qc = blockIdx.x & 31;
  const float* src = pos + b * 6144;
  for (int u = tid; u < 6144; u += 256) ps[u] = src[u];
  __syncthreads();
  for (int u = tid; u < 2048; u += 256) {
    float x = ps[u * 3], y = ps[u * 3 + 1], z = ps[u * 3 + 2];
    sqs[u] = fmaf(z, z, fmaf(y, y, x * x));
  }
  __syncthreads();
  int q = tid & 63, sub = tid >> 6;
  int qi = qc * 64 + q;
  float qx = ps[qi * 3], qy = ps[qi * 3 + 1], qz = ps[qi * 3 + 2];
  float qsq = sqs[qi];
  float bd[5] = {1e30f, 1e30f, 1e30f, 1e30f, 1e30f};
  int bi[5] = {0, 0, 0, 0, 0};
  int j0 = sub * 512;
  for (int j = j0; j < j0 + 512; ++j) {
    float px = ps[j * 3], py = ps[j * 3 + 1], pz = ps[j * 3 + 2];
    float dot = fmaf(qz, pz, fmaf(qy, py, qx * px));
    float d = (qsq + sqs[j]) - 2.0f * dot;
    knn_insert(bd, bi, d, j);
  }
  for (int half = 2; half >= 1; half >>= 1) {
    __syncthreads();
    if (sub >= half && sub < 2 * half) {
      int slot = (q * 2 + (sub - half)) * 5;
#pragma unroll
      for (int k = 0; k < 5; ++k) { md[slot + k] = bd[k]; mi[slot + k] = bi[k]; }
    }
    __syncthreads();
    if (sub < half) {
      int slot = (q * 2 + sub) * 5;
#pragma unroll
      for (int k = 0; k < 5; ++k) knn_insert(bd, bi, md[slot + k], mi[slot + k]);
    }
  }
  if (sub == 0) {
    int* op = idx1 + (b * 2048 + qi) * 5;
#pragma unroll
    for (int k = 0; k < 5; ++k) op[k] = bi[k];
  }
}

// ---------------- Kernel 1b: per-point u/v for EdgeConv1 layer-1 ----------------
__global__ __launch_bounds__(256) void k_uv(const float* __restrict__ pos,
                                            const float* __restrict__ w1a,
                                            const float* __restrict__ b1a,
                                            float* __restrict__ ut,
                                            float* __restrict__ v) {
  __shared__ float wAs[384];
  __shared__ float bs[64];
  int tid = threadIdx.x;
  for (int u = tid; u < 384; u += 256) wAs[u] = w1a[u];
  if (tid < 64) bs[tid] = b1a[tid];
  __syncthreads();
  int lane = tid & 63, fq = tid >> 6;
  int p = blockIdx.x * 64 + lane;
  int b = p >> 11, nloc = p & 2047;
  float x0 = pos[p * 3], x1 = pos[p * 3 + 1], x2 = pos[p * 3 + 2];
  float uu[16], vv[16];
#pragma unroll
  for (int m = 0; m < 16; ++m) {
    int f = fq * 16 + m;
    float wt0 = wAs[f], wt1 = wAs[64 + f], wt2 = wAs[128 + f];
    float wb0 = wAs[192 + f], wb1 = wAs[256 + f], wb2 = wAs[320 + f];
    float uval = bs[f];
    uval = fmaf(x0, wt0 - wb0, uval);
    uval = fmaf(x1, wt1 - wb1, uval);
    uval = fmaf(x2, wt2 - wb2, uval);
    uu[m] = uval;
    vv[m] = fmaf(x2, wb2, fmaf(x1, wb1, x0 * wb0));
  }
#pragma unroll
  for (int m = 0; m < 16; ++m)
    ut[((size_t)b * 64 + fq * 16 + m) * 2048 + nloc] = uu[m];
#pragma unroll
  for (int it = 0; it < 4; ++it)
    *(float4*)(v + (size_t)p * 64 + fq * 16 + it * 4) = *(const float4*)(vv + it * 4);
}

// ---------------- Kernel 2: EdgeConv1 layers 2/3 as 4x4-blocked GEMM ----------------
__global__ __launch_bounds__(256) void k_edge1(
    const int* __restrict__ idx1, const float* __restrict__ ut,
    const float* __restrict__ v,
    const float* __restrict__ s1a, const float* __restrict__ h1a,
    const float* __restrict__ w1b, const float* __restrict__ b1b,
    const float* __restrict__ s1b, const float* __restrict__ h1b,
    const float* __restrict__ w1c, const float* __restrict__ b1c,
    const float* __restrict__ s1c, const float* __restrict__ h1c,
    __bf16* __restrict__ xh, __bf16* __restrict__ xl,
    float* __restrict__ sqo, __bf16* __restrict__ xb) {
  __shared__ __align__(16) float h1t[64 * 68];
  __shared__ __align__(16) float h2t[64 * 68];
  __shared__ __align__(16) float wB[4096], wC[4096];
  __shared__ float cA[128], cB[192], cC[192];
  __shared__ float red[64 * 17];
  int tid = threadIdx.x;
  for (int u = tid; u < 4096; u += 256) { wB[u] = w1b[u]; wC[u] = w1c[u]; }
  if (tid < 64) {
    cA[tid] = s1a[tid]; cA[64 + tid] = h1a[tid];
    cB[tid] = b1b[tid]; cB[64 + tid] = s1b[tid]; cB[128 + tid] = h1b[tid];
    cC[tid] = b1c[tid]; cC[64 + tid] = s1c[tid]; cC[128 + tid] = h1c[tid];
  }
  int p0 = blockIdx.x * 64;
  int b = p0 >> 11, nloc0 = p0 & 2047;
  size_t bb = (size_t)b * 2048;
  int e = tid & 63, fq = tid >> 6;
  int cg = tid >> 4, pg = tid & 15;
  float amax[4][4];
#pragma unroll
  for (int i = 0; i < 4; ++i)
#pragma unroll
    for (int j = 0; j < 4; ++j) amax[i][j] = -3.4e38f;
  __syncthreads();
  for (int k = 0; k < 5; ++k) {
    {
      int j = idx1[(p0 + e) * 5 + k];
      const float* vrow = v + (bb + j) * 64 + fq * 16;
#pragma unroll
      for (int it = 0; it < 4; ++it) {
        float4 vv = *(const float4*)(vrow + it * 4);
        float vr[4] = {vv.x, vv.y, vv.z, vv.w};
#pragma unroll
        for (int m = 0; m < 4; ++m) {
          int f = fq * 16 + it * 4 + m;
          float uval = ut[((size_t)b * 64 + f) * 2048 + nloc0 + e];
          h1t[f * 68 + e] = relu_(uval + vr[m]) * cA[f] + cA[64 + f];
        }
      }
    }
    __syncthreads();
    {
      float acc[4][4] = {{0, 0, 0, 0}, {0, 0, 0, 0}, {0, 0, 0, 0}, {0, 0, 0, 0}};
#pragma unroll 4
      for (int f = 0; f < 64; ++f) {
        float4 av = *(const float4*)(h1t + f * 68 + pg * 4);
        float4 wv = *(const float4*)(wB + f * 64 + cg * 4);
        float a[4] = {av.x, av.y, av.z, av.w};
        float w[4] = {wv.x, wv.y, wv.z, wv.w};
#pragma unroll
        for (int ii = 0; ii < 4; ++ii)
#pragma unroll
          for (int jj = 0; jj < 4; ++jj)
            acc[ii][jj] = fmaf(a[ii], w[jj], acc[ii][jj]);
      }
#pragma unroll
      for (int jj = 0; jj < 4; ++jj) {
        int c = cg * 4 + jj;
        float bv = cB[c], sv = cB[64 + c], hv = cB[128 + c];
#pragma unroll
        for (int ii = 0; ii < 4; ++ii)
          h2t[c * 68 + pg * 4 + ii] = relu_(acc[ii][jj] + bv) * sv + hv;
      }
    }
    __syncthreads();
    {
      float acc[4][4] = {{0, 0, 0, 0}, {0, 0, 0, 0}, {0, 0, 0, 0}, {0, 0, 0, 0}};
#pragma unroll 4
      for (int f = 0; f < 64; ++f) {
        float4 av = *(const float4*)(h2t + f * 68 + pg * 4);
        float4 wv = *(const float4*)(wC + f * 64 + cg * 4);
        float a[4] = {av.x, av.y, av.z, av.w};
        float w[4] = {wv.x, wv.y, wv.z, wv.w};
#pragma unroll
        for (int ii = 0; ii < 4; ++ii)
#pragma unroll
          for (int jj = 0; jj < 4; ++jj)
            acc[ii][jj] = fmaf(a[ii], w[jj], acc[ii][jj]);
      }
#pragma unroll
      for (int ii = 0; ii < 4; ++ii)
#pragma unroll
        for (int jj = 0; jj < 4; ++jj)
          amax[ii][jj] = fmaxf(amax[ii][jj], acc[ii][jj]);
    }
    __syncthreads();
  }
#pragma unroll
  for (int ii = 0; ii < 4; ++ii) {
    int n = p0 + pg * 4 + ii;
    float sqp = 0.f;
    __bf16 oh[4], ol[4], ob[4];
#pragma unroll
    for (int jj = 0; jj < 4; ++jj) {
      int c = cg * 4 + jj;
      float val = relu_(amax[ii][jj] + cC[c]) * cC[64 + c] + cC[128 + c];
      sqp = fmaf(val, val, sqp);
      __bf16 h = (__bf16)val;
      oh[jj] = h;
      ol[jj] = (__bf16)(val - (float)h);
      ob[jj] = h;
    }
    *(uint2*)(xh + (size_t)n * 64 + cg * 4) = *(const uint2*)oh;
    *(uint2*)(xl + (size_t)n * 64 + cg * 4) = *(const uint2*)ol;
    *(uint2*)(xb + (size_t)n * 192 + cg * 4) = *(const uint2*)ob;
    red[(pg * 4 + ii) * 17 + cg] = sqp;
  }
  __syncthreads();
  if (tid < 64) {
    float s = 0.f;
#pragma unroll
    for (int g = 0; g < 16; ++g) s += red[tid * 17 + g];
    sqo[p0 + tid] = s;
  }
}

// ---------------- Kernel 3: kNN on x1 via MFMA hi/lo + branchless EXACT top-5 ----------------
__global__ __launch_bounds__(256) void k_knn2(const __bf16* __restrict__ xh,
                                              const __bf16* __restrict__ xl,
                                              const float* __restrict__ sq,
                                              int* __restrict__ idx2) {
  __shared__ __align__(16) __bf16 Bh[64 * 72];
  __shared__ __align__(16) __bf16 Bl[64 * 72];
  __shared__ float sqs[2048];
  int tid = threadIdx.x;
  int w = tid >> 6, lane = tid & 63;
  int quad = lane >> 4, lm = lane & 15;
  int b = blockIdx.x >> 5, qc = blockIdx.x & 31;
  int q0 = qc * 64;
  size_t bb = (size_t)b * 2048;
  for (int u = tid; u < 512; u += 256)
    *(float4*)(sqs + u * 4) = *(const float4*)(sq + bb + u * 4);
  const __bf16* qh = xh + (bb + q0 + w * 16 + lm) * 64 + quad * 8;
  const __bf16* ql = xl + (bb + q0 + w * 16 + lm) * 64 + quad * 8;
  bf16x8 Ah0 = *(const bf16x8*)(qh);
  bf16x8 Ah1 = *(const bf16x8*)(qh + 32);
  bf16x8 Al0 = *(const bf16x8*)(ql);
  bf16x8 Al1 = *(const bf16x8*)(ql + 32);
  __syncthreads();
  float qsq[4];
#pragma unroll
  for (int r = 0; r < 4; ++r) qsq[r] = sqs[q0 + w * 16 + quad * 4 + r];
  float bd[4][5];
  int bi[4][5];
#pragma unroll
  for (int r = 0; r < 4; ++r)
#pragma unroll
    for (int k = 0; k < 5; ++k) { bd[r][k] = 1e30f; bi[r][k] = 0; }
  for (int ct = 0; ct < 32; ++ct) {
#pragma unroll
    for (int pass = 0; pass < 2; ++pass) {
      int unit = pass * 256 + tid;
      int n = unit >> 3, cc = unit & 7;
      const __bf16* gsrc = xh + (bb + ct * 64 + n) * 64 + cc * 8;
      const __bf16* gsrl = xl + (bb + ct * 64 + n) * 64 + cc * 8;
      *(uint4*)(Bh + n * 72 + cc * 8) = *(const uint4*)gsrc;
      *(uint4*)(Bl + n * 72 + cc * 8) = *(const uint4*)gsrl;
    }
    __syncthreads();
#pragma unroll
    for (int nt = 0; nt < 4; ++nt) {
      const __bf16* bph = Bh + (nt * 16 + lm) * 72 + quad * 8;
      const __bf16* bpl = Bl + (nt * 16 + lm) * 72 + quad * 8;
      bf16x8 Bh0 = *(const bf16x8*)(bph);
      bf16x8 Bh1 = *(const bf16x8*)(bph + 32);
      bf16x8 Bl0 = *(const bf16x8*)(bpl);
      bf16x8 Bl1 = *(const bf16x8*)(bpl + 32);
      f32x4 acc = {0.f, 0.f, 0.f, 0.f};
      acc = __builtin_amdgcn_mfma_f32_16x16x32_bf16(Ah0, Bh0, acc, 0, 0, 0);
      acc = __builtin_amdgcn_mfma_f32_16x16x32_bf16(Ah1, Bh1, acc, 0, 0, 0);
      acc = __builtin_amdgcn_mfma_f32_16x16x32_bf16(Ah0, Bl0, acc, 0, 0, 0);
      acc = __builtin_amdgcn_mfma_f32_16x16x32_bf16(Ah1, Bl1, acc, 0, 0, 0);
      acc = __builtin_amdgcn_mfma_f32_16x16x32_bf16(Al0, Bh0, acc, 0, 0, 0);
      acc = __builtin_amdgcn_mfma_f32_16x16x32_bf16(Al1, Bh1, acc, 0, 0, 0);
      int cid = ct * 64 + nt * 16 + lm;
      float csq = sqs[cid];
#pragma unroll
      for (int r = 0; r < 4; ++r) {
        float d = (qsq[r] + csq) - 2.0f * acc[r];
        knn_insert_bl(bd[r], bi[r], d, cid);
      }
    }
    __syncthreads();
  }
  // merge 16 lm-partials per row via shuffle butterfly (branchless exact inserts)
  for (int m = 1; m <= 8; m <<= 1) {
#pragma unroll
    for (int r = 0; r < 4; ++r) {
      float od[5]; int oi[5];
#pragma unroll
      for (int k = 0; k < 5; ++k) {
        od[k] = __shfl_xor(bd[r][k], m);
        oi[k] = __shfl_xor(bi[r][k], m);
      }
#pragma unroll
      for (int k = 0; k < 5; ++k) knn_insert_bl(bd[r], bi[r], od[k], oi[k]);
    }
  }
  if (lm == 0) {
#pragma unroll
    for (int r = 0; r < 4; ++r) {
      int qi = q0 + w * 16 + quad * 4 + r;
      int* op = idx2 + (bb + qi) * 5;
#pragma unroll
      for (int k = 0; k < 5; ++k) op[k] = bi[r][k];
    }
  }
}

// ---------------- Kernel 4a: P = x1@(W1-W2), Q = x1@W2 (x1 = hi+lo) ----------------
__global__ __launch_bounds__(256) void k_pq(const __bf16* __restrict__ xh,
                                            const __bf16* __restrict__ xl,
                                            const float* __restrict__ w2,
                                            __bf16* __restrict__ Pb,
                                            __bf16* __restrict__ Qb) {
  __shared__ __align__(16) float ins[4096];
  int tid = threadIdx.x;
  int pt = blockIdx.x >> 2, oc = blockIdx.x & 3;
  int n0 = pt * 64;
#pragma unroll
  for (int pass = 0; pass < 2; ++pass) {
    int unit = pass * 256 + tid;
    int n = unit >> 3, cc = unit & 7;
    bf16x8 h = *(const bf16x8*)(xh + ((size_t)(n0 + n)) * 64 + cc * 8);
    bf16x8 l = *(const bf16x8*)(xl + ((size_t)(n0 + n)) * 64 + cc * 8);
#pragma unroll
    for (int j = 0; j < 8; ++j)
      ins[(cc * 8 + j) * 64 + n] = (float)h[j] + (float)l[j];
  }
  __syncthreads();
  int cg = tid >> 4, pg = tid & 15;
  int vcol = oc * 64 + cg * 4;
  bool isP = (oc < 2);
  int col = isP ? vcol : (vcol - 128);
  float acc[4][4] = {{0, 0, 0, 0}, {0, 0, 0, 0}, {0, 0, 0, 0}, {0, 0, 0, 0}};
#pragma unroll 4
  for (int k = 0; k < 64; ++k) {
    float4 av = *(const float4*)(ins + k * 64 + pg * 4);
    float a[4] = {av.x, av.y, av.z, av.w};
    float4 wBv = *(const float4*)(w2 + (64 + k) * 128 + col);
    float wv[4];
    if (isP) {
      float4 wAv = *(const float4*)(w2 + k * 128 + col);
      wv[0] = wAv.x - wBv.x; wv[1] = wAv.y - wBv.y;
      wv[2] = wAv.z - wBv.z; wv[3] = wAv.w - wBv.w;
    } else {
      wv[0] = wBv.x; wv[1] = wBv.y; wv[2] = wBv.z; wv[3] = wBv.w;
    }
#pragma unroll
    for (int ii = 0; ii < 4; ++ii)
#pragma unroll
      for (int jj = 0; jj < 4; ++jj)
        acc[ii][jj] = fmaf(a[ii], wv[jj], acc[ii][jj]);
  }
  __bf16* base = (isP ? Pb : Qb);
#pragma unroll
  for (int ii = 0; ii < 4; ++ii) {
    int n = n0 + pg * 4 + ii;
    __bf16 o[4];
#pragma unroll
    for (int jj = 0; jj < 4; ++jj) o[jj] = (__bf16)acc[ii][jj];
    *(uint2*)(base + (size_t)n * 128 + col) = *(const uint2*)o;
  }
}

// ---------------- Kernel 4p: repack wl -> MFMA-B frag order bf16 ----------------
__global__ __launch_bounds__(256) void k_prep(const float* __restrict__ wl,
                                              __bf16* __restrict__ wlb) {
  int t = blockIdx.x * 256 + threadIdx.x;
  int nt = t / 3072;
  int rem = t - nt * 3072;
  int ks = rem / 512;
  int rem2 = rem - ks * 512;
  int nb = rem2 >> 6, lane = rem2 & 63;
  int k0 = ks * 32 + (lane >> 4) * 8;
  int n = nt * 128 + nb * 16 + (lane & 15);
  __bf16 o[8];
#pragma unroll
  for (int j = 0; j < 8; ++j) o[j] = (__bf16)wl[(k0 + j) * 1024 + n];
  *(uint4*)(wlb + (size_t)t * 8) = *(const uint4*)o;
}

// ---------------- Kernel 4b: gather-max + activation -> xb bf16 [n][64:192] ----------------
__global__ __launch_bounds__(256) void k_gmax(const __bf16* __restrict__ Pb,
                                              const __bf16* __restrict__ Qb,
                                              const int* __restrict__ idx2,
                                              const float* __restrict__ b2,
                                              const float* __restrict__ s2,
                                              const float* __restrict__ h2v,
                                              __bf16* __restrict__ xb) {
  int tid = threadIdx.x;
  int c = tid & 127, p = tid >> 7;
  int n = blockIdx.x * 2 + p;
  int b = n >> 11;
  const int* ip = idx2 + n * 5;
  float m = -3.4e38f;
#pragma unroll
  for (int k = 0; k < 5; ++k) {
    int j = ip[k];
    m = fmaxf(m, (float)Qb[((size_t)(b * 2048 + j)) * 128 + c]);
  }
  float v = (float)Pb[(size_t)n * 128 + c] + m + b2[c];
  xb[(size_t)n * 192 + 64 + c] = (__bf16)(relu_(v) * s2[c] + h2v[c]);
}

// ---------------- Kernel 5: bf16 MFMA GEMM fused point-max ----------------
__global__ __launch_bounds__(256) void k_linl_mfma(const __bf16* __restrict__ xb,
                                                   const __bf16* __restrict__ wlb,
                                                   float* __restrict__ pool_part) {
  __shared__ __align__(16) __bf16 Al[4096];
  __shared__ __align__(16) __bf16 Bl[4096];
  __shared__ float red[256];
  int tid = threadIdx.x;
  int w = tid >> 6, lane = tid & 63;
  int mt = blockIdx.x >> 3, nt = blockIdx.x & 7;
  int n0 = mt << 7;
  int wm = w & 1, wn = w >> 1;
  int quad = lane >> 4, lm = lane & 15;
  f32x4 acc[4][4];
#pragma unroll
  for (int i = 0; i < 4; ++i)
#pragma unroll
    for (int j = 0; j < 4; ++j) acc[i][j] = (f32x4){0.f, 0.f, 0.f, 0.f};
  for (int ks = 0; ks < 6; ++ks) {
    __syncthreads();
#pragma unroll
    for (int u = 0; u < 2; ++u) {
      int mb = w * 2 + u;
      const uint4* ga = (const uint4*)(xb + (size_t)(n0 + mb * 16 + lm) * 192 + ks * 32 + quad * 8);
      *(uint4*)(Al + (mb * 64 + lane) * 8) = *ga;
      const uint4* gb = (const uint4*)(wlb + ((((size_t)nt * 6 + ks) * 8 + mb) * 64 + lane) * 8);
      *(uint4*)(Bl + (mb * 64 + lane) * 8) = *gb;
    }
    __syncthreads();
    bf16x8 af[4], bfr[4];
#pragma unroll
    for (int i = 0; i < 4; ++i) {
      af[i] = *(const bf16x8*)(Al + ((wm * 4 + i) * 64 + lane) * 8);
      bfr[i] = *(const bf16x8*)(Bl + ((wn * 4 + i) * 64 + lane) * 8);
    }
#pragma unroll
    for (int i = 0; i < 4; ++i)
#pragma unroll
      for (int j = 0; j < 4; ++j)
        acc[i][j] = __builtin_amdgcn_mfma_f32_16x16x32_bf16(af[i], bfr[j], acc[i][j], 0, 0, 0);
  }
  float pm[4];
#pragma unroll
  for (int j = 0; j < 4; ++j) {
    float m = -3.4e38f;
#pragma unroll
    for (int i = 0; i < 4; ++i)
#pragma unroll
      for (int r = 0; r < 4; ++r) m = fmaxf(m, acc[i][j][r]);
    m = fmaxf(m, __shfl_xor(m, 16));
    m = fmaxf(m, __shfl_xor(m, 32));
    pm[j] = m;
  }
  __syncthreads();
  if (quad == 0) {
#pragma unroll
    for (int j = 0; j < 4; ++j) red[w * 64 + j * 16 + lm] = pm[j];
  }
  __syncthreads();
  if (tid < 128) {
    int wn2 = tid >> 6, cc = tid & 63;
    float v = fmaxf(red[(wn2 * 2) * 64 + cc], red[(wn2 * 2 + 1) * 64 + cc]);
    pool_part[(size_t)mt * 1024 + nt * 128 + wn2 * 64 + cc] = v;
  }
}

// ---------------- Kernel 6: head MLP ----------------
__global__ __launch_bounds__(256) void k_head(
    const float* __restrict__ pool_part, const float* __restrict__ bl,
    const float* __restrict__ sl, const float* __restrict__ hl,
    const float* __restrict__ wm1, const float* __restrict__ bm1,
    const float* __restrict__ sm1, const float* __restrict__ hm1,
    const float* __restrict__ wm2, const float* __restrict__ bm2,
    const float* __restrict__ sm2, const float* __restrict__ hm2,
    const float* __restrict__ wout, const float* __restrict__ bout,
    float* __restrict__ out) {
  __shared__ float p_s[1024], h1_s[512], h2_s[256];
  int b = blockIdx.x, tid = threadIdx.x;
  for (int c = tid; c < 1024; c += 256) {
    float m = -3.4e38f;
#pragma unroll 4
    for (int t = 0; t < 16; ++t)
      m = fmaxf(m, pool_part[(size_t)(b * 16 + t) * 1024 + c]);
    p_s[c] = relu_(m + bl[c]) * sl[c] + hl[c];
  }
  __syncthreads();
  for (int c = tid; c < 512; c += 256) {
    float a0 = 0, a1 = 0, a2 = 0, a3 = 0;
    for (int f = 0; f < 1024; f += 4) {
      a0 = fmaf(p_s[f], wm1[f * 512 + c], a0);
      a1 = fmaf(p_s[f + 1], wm1[(f + 1) * 512 + c], a1);
      a2 = fmaf(p_s[f + 2], wm1[(f + 2) * 512 + c], a2);
      a3 = fmaf(p_s[f + 3], wm1[(f + 3) * 512 + c], a3);
    }
    float a = (a0 + a1) + (a2 + a3);
    h1_s[c] = relu_(a + bm1[c]) * sm1[c] + hm1[c];
  }
  __syncthreads();
  if (tid < 256) {
    float a0 = 0, a1 = 0, a2 = 0, a3 = 0;
    for (int f = 0; f < 512; f += 4) {
      a0 = fmaf(h1_s[f], wm2[f * 256 + tid], a0);
      a1 = fmaf(h1_s[f + 1], wm2[(f + 1) * 256 + tid], a1);
      a2 = fmaf(h1_s[f + 2], wm2[(f + 2) * 256 + tid], a2);
      a3 = fmaf(h1_s[f + 3], wm2[(f + 3) * 256 + tid], a3);
    }
    float a = (a0 + a1) + (a2 + a3);
    h2_s[tid] = relu_(a + bm2[tid]) * sm2[tid] + hm2[tid];
  }
  __syncthreads();
  if (tid < 2) {
    float a0 = 0, a1 = 0;
    for (int f = 0; f < 256; f += 2) {
      a0 = fmaf(h2_s[f], wout[f * 2 + tid], a0);
      a1 = fmaf(h2_s[f + 1], wout[(f + 1) * 2 + tid], a1);
    }
    out[b * 2 + tid] = (a0 + a1) + bout[tid];
  }
}

extern "C" void kernel_launch(void* const* d_in, const int* in_sizes, int n_in,
                              void* d_out, int out_size, void* d_ws, size_t ws_size,
                              hipStream_t stream) {
  const float* pos = (const float*)d_in[0];
  const float* w1a = (const float*)d_in[1];
  const float* b1a = (const float*)d_in[2];
  const float* s1a = (const float*)d_in[3];
  const float* h1a = (const float*)d_in[4];
  const float* w1b = (const float*)d_in[5];
  const float* b1b = (const float*)d_in[6];
  const float* s1b = (const float*)d_in[7];
  const float* h1b = (const float*)d_in[8];
  const float* w1c = (const float*)d_in[9];
  const float* b1c = (const float*)d_in[10];
  const float* s1c = (const float*)d_in[11];
  const float* h1c = (const float*)d_in[12];
  const float* w2 = (const float*)d_in[13];
  const float* b2 = (const float*)d_in[14];
  const float* s2 = (const float*)d_in[15];
  const float* h2 = (const float*)d_in[16];
  const float* wl = (const float*)d_in[17];
  const float* bl = (const float*)d_in[18];
  const float* sl = (const float*)d_in[19];
  const float* hl = (const float*)d_in[20];
  const float* wm1 = (const float*)d_in[21];
  const float* bm1 = (const float*)d_in[22];
  const float* sm1 = (const float*)d_in[23];
  const float* hm1 = (const float*)d_in[24];
  const float* wm2 = (const float*)d_in[25];
  const float* bm2 = (const float*)d_in[26];
  const float* sm2 = (const float*)d_in[27];
  const float* hm2 = (const float*)d_in[28];
  const float* wout = (const float*)d_in[29];
  const float* bout = (const float*)d_in[30];
  float* out = (float*)d_out;

  float* base = (float*)d_ws;
  __bf16* xh = (__bf16*)base;
  __bf16* xl = (__bf16*)(base + 2097152);
  float* PbF = base + 4194304;
  float* QbF = PbF + 4194304;
  float* xbF = QbF + 4194304;
  int* idx = (int*)(xbF + 6291456);
  float* sq = (float*)(idx + 327680);
  __bf16* Pb = (__bf16*)PbF;
  __bf16* Qb = (__bf16*)QbF;
  __bf16* xb = (__bf16*)xbF;
  float* ut = PbF;
  float* vv = QbF;
  __bf16* wlb = (__bf16*)base;
  float* pool_part = base + 131072;

  k_knn1<<<1024, 256, 0, stream>>>(pos, idx);
  k_uv<<<1024, 256, 0, stream>>>(pos, w1a, b1a, ut, vv);
  k_edge1<<<1024, 256, 0, stream>>>(idx, ut, vv, s1a, h1a, w1b, b1b, s1b, h1b,
                                    w1c, b1c, s1c, h1c, xh, xl, sq, xb);
  k_knn2<<<1024, 256, 0, stream>>>(xh, xl, sq, idx);
  k_pq<<<4096, 256, 0, stream>>>(xh, xl, w2, Pb, Qb);
  k_prep<<<96, 256, 0, stream>>>(wl, wlb);
  k_gmax<<<32768, 256, 0, stream>>>(Pb, Qb, idx, b2, s2, h2, xb);
  k_linl_mfma<<<4096, 256, 0, stream>>>(xb, wlb, pool_part);
  k_head<<<32, 256, 0, stream>>>(pool_part, bl, sl, hl, wm1, bm1, sm1, hm1, wm2,
                                 bm2, sm2, hm2, wout, bout, out);
}